// Round 7
// baseline (666.034 us; speedup 1.0000x reference)
//
#include <hip/hip_runtime.h>
#include <math.h>

#define D_MODEL 768
#define D_HID   1536
#define N_BATCH 8
#define SEQLEN  2048
#define NROWS   (N_BATCH*SEQLEN)   // 16384

typedef unsigned short u16;
typedef __attribute__((ext_vector_type(8))) short bfrag;   // 8 x bf16 (4 VGPRs)
typedef __attribute__((ext_vector_type(4))) float facc;    // 4 x fp32 acc

__device__ __forceinline__ u16 f2bf(float f) {
  unsigned u = __float_as_uint(f);
  u += 0x7fffu + ((u >> 16) & 1u);
  return (u16)(u >> 16);
}
__device__ __forceinline__ float bf2f(u16 u) {
  return __uint_as_float((unsigned)u << 16);
}

__device__ __forceinline__ void async16(const void* g, void* l) {
  __builtin_amdgcn_global_load_lds((const __attribute__((address_space(1))) void*)g,
                                   (__attribute__((address_space(3))) void*)l,
                                   16, 0, 0);
}

// ---------------- fused f32->bf16 conversion of all operands + bias concat ----------------
__global__ __launch_bounds__(256) void cvt_all(
    const float* __restrict__ x,  const float* __restrict__ Wq,
    const float* __restrict__ Wk, const float* __restrict__ Wv,
    const float* __restrict__ Wp, const float* __restrict__ W1,
    const float* __restrict__ W2, const float* __restrict__ bq,
    const float* __restrict__ bk, const float* __restrict__ bv,
    u16* __restrict__ XB, u16* __restrict__ WQKV, u16* __restrict__ WPB,
    u16* __restrict__ W1B, u16* __restrict__ W2B, float* __restrict__ BQKV) {
  long i = (long)blockIdx.x * 256 + threadIdx.x;
  const float* src; u16* dst; long off;
  if      (i < 3145728) { src = x;  dst = XB;             off = i; }
  else if (i < 3293184) { src = Wq; dst = WQKV;           off = i - 3145728; }
  else if (i < 3440640) { src = Wk; dst = WQKV + 589824;  off = i - 3293184; }
  else if (i < 3588096) { src = Wv; dst = WQKV + 1179648; off = i - 3440640; }
  else if (i < 3735552) { src = Wp; dst = WPB;            off = i - 3588096; }
  else if (i < 4030464) { src = W1; dst = W1B;            off = i - 3735552; }
  else if (i < 4325376) { src = W2; dst = W2B;            off = i - 4030464; }
  else if (i < 4325952) {
    long j = i - 4325376;   // 0..575 -> BQKV[j] (f4), concatenated bq|bk|bv
    const float* s = (j < 192) ? bq : (j < 384) ? bk : bv;
    long o = (j < 192) ? j : (j < 384) ? j - 192 : j - 384;
    ((float4*)BQKV)[j] = ((const float4*)s)[o];
    return;
  } else return;
  float4 v = ((const float4*)src)[off];
  ushort4 o4;
  o4.x = f2bf(v.x); o4.y = f2bf(v.y); o4.z = f2bf(v.z); o4.w = f2bf(v.w);
  *reinterpret_cast<ushort4*>(dst + off * 4) = o4;
}

// ------- GEMM A: C[M,N] = A[M,K]*B[N,K]^T, tile 128x256, BK=64, 8 waves, 16x16x32 MFMA -------
enum { EPI_EXP = 1, EPI_DIV = 2, EPI_GELU = 4, EPI_QKV = 5, EPI_RES = 6 };

template<int EPI>
__global__ __launch_bounds__(512, 4)
void gemm_bt(const u16* __restrict__ Aall, const u16* __restrict__ Ball,
             void* __restrict__ Cout,
             int M, int N, int K,
             long sA, long sB, long sC,
             const float* __restrict__ bias,
             const u16* __restrict__ resid,   // EPI_RES: residual; EPI_QKV: VT out
             float* __restrict__ lsum,
             float scale)
{
  // 64 KB: [0,16K)=As(128x64), [16K,48K)=Bs(256x64) during K-loop;
  // epilogue (after barrier): 8 x 8 KB per-wave regions.
  __shared__ __align__(16) char smem[65536];
  u16* As = (u16*)smem;
  u16* Bs = (u16*)(smem + 16384);

  const int z = blockIdx.z;
  const u16* A = Aall + (long)z * sA;
  const u16* B = Ball + (long)z * sB;
  const int bm = blockIdx.x, bn = blockIdx.y;
  const int tid = (int)threadIdx.x;
  const int lane = tid & 63, wv = tid >> 6;          // 8 waves
  const int wr = wv >> 2, wc = wv & 3;               // wave grid 2x4 (64x64 each)

  facc acc[4][4] = {};

  const int srow = tid >> 3;                          // 0..63
  const int scol = (((tid & 7) ^ (srow & 7)) << 3);   // XOR-swizzled source elem offset
  const u16* Abase = A + (long)(bm * 128) * K;
  const u16* Bbase = B + (long)(bn * 256) * K;

  const int fr = lane & 15;
  const int g0 = lane >> 4;                           // base k-chunk (0..3)

  for (int k0 = 0; k0 < K; k0 += 64) {
    __syncthreads();
#pragma unroll
    for (int p = 0; p < 2; ++p)    // A: 128 rows
      async16(Abase + (long)(p * 64 + srow) * K + k0 + scol, As + (p * 512 + wv * 64) * 8);
#pragma unroll
    for (int p = 0; p < 4; ++p)    // B: 256 rows
      async16(Bbase + (long)(p * 64 + srow) * K + k0 + scol, Bs + (p * 512 + wv * 64) * 8);
    __syncthreads();
#pragma unroll
    for (int h = 0; h < 2; ++h) {
      bfrag af[4], bfv[4];
      const int gh = g0 + h * 4;
#pragma unroll
      for (int i = 0; i < 4; ++i) {
        const int r = wr * 64 + i * 16 + fr;
        af[i] = *(const bfrag*)(As + r * 64 + ((gh ^ (r & 7)) << 3));
      }
#pragma unroll
      for (int j = 0; j < 4; ++j) {
        const int r = wc * 64 + j * 16 + fr;
        bfv[j] = *(const bfrag*)(Bs + r * 64 + ((gh ^ (r & 7)) << 3));
      }
#pragma unroll
      for (int i = 0; i < 4; ++i)
#pragma unroll
        for (int j = 0; j < 4; ++j)
          acc[i][j] = __builtin_amdgcn_mfma_f32_16x16x32_bf16(af[i], bfv[j], acc[i][j], 0, 0, 0);
    }
  }

  // ---- epilogue ----  16x16 C/D layout: col = lane&15, row = (lane>>4)*4 + reg
  __syncthreads();   // done reading As/Bs; smem becomes 8 x 8KB wave staging
  const int rb = bm * 128 + wr * 64;
  const int cb = bn * 256 + wc * 64;
  const int quad = lane >> 4;

  if constexpr (EPI == EPI_QKV) {
    const int c64 = bn * 4 + wc;         // 0..35
    const int which = c64 / 12;          // 0=Q,1=K,2=V
    float bj[4];
#pragma unroll
    for (int j = 0; j < 4; ++j) bj[j] = bias[cb + j * 16 + fr];
    if (which == 2) {
      // V: direct transposed register stores -> VT[z][dim][seq]
      u16* VT_ = (u16*)resid;
      const int zb = rb >> 11;
      const int seqb = (rb & 2047) + quad * 4;
      const int dimb = (c64 - 24) * 64;
#pragma unroll
      for (int i = 0; i < 4; ++i) {
#pragma unroll
        for (int j = 0; j < 4; ++j) {
          const int dim = dimb + j * 16 + fr;
          ushort4 o;
          o.x = f2bf(acc[i][j][0] + bj[j]);
          o.y = f2bf(acc[i][j][1] + bj[j]);
          o.z = f2bf(acc[i][j][2] + bj[j]);
          o.w = f2bf(acc[i][j][3] + bj[j]);
          *reinterpret_cast<ushort4*>(VT_ + (long)zb * D_MODEL * SEQLEN +
                                      (long)dim * SEQLEN + seqb + i * 16) = o;
        }
      }
      return;
    }
    // Q/K: stage in per-wave LDS then coalesced int4 stores
    u16* ep16 = (u16*)(smem + wv * 8192);
    u16* Cg = (u16*)Cout + (long)which * NROWS * D_MODEL;
    const int cbo = (c64 - which * 12) * 64;
#pragma unroll
    for (int i = 0; i < 4; ++i)
#pragma unroll
      for (int r = 0; r < 4; ++r) {
        const int lrow = i * 16 + quad * 4 + r;
#pragma unroll
        for (int j = 0; j < 4; ++j)
          ep16[lrow * 64 + j * 16 + fr] = f2bf(acc[i][j][r] + bj[j]);
      }
#pragma unroll
    for (int it = 0; it < 8; ++it) {
      const int lr = it * 8 + (lane >> 3);
      const int ch = (lane & 7) << 3;
      int4 d = *(const int4*)(ep16 + lr * 64 + ch);
      *reinterpret_cast<int4*>(Cg + (long)(rb + lr) * D_MODEL + cbo + ch) = d;
    }
  } else {
    // EXP / GELU: bf16 out via staged LDS
    u16* ep16 = (u16*)(smem + wv * 8192);
    u16* Cg = (u16*)Cout + (long)z * sC;
    float bj[4];
    if constexpr (EPI == EPI_GELU) {
#pragma unroll
      for (int j = 0; j < 4; ++j) bj[j] = bias[cb + j * 16 + fr];
    }
#pragma unroll
    for (int i = 0; i < 4; ++i) {
#pragma unroll
      for (int r = 0; r < 4; ++r) {
        const int lrow = i * 16 + quad * 4 + r;
        const int row = rb + lrow;
        float rs = 0.f;
#pragma unroll
        for (int j = 0; j < 4; ++j) {
          float v = acc[i][j][r];
          float outv;
          if constexpr (EPI == EPI_EXP) {
            outv = __expf(v * scale);
            rs += outv;
          } else { // EPI_GELU
            float t = v + bj[j];
            outv = 0.5f * t * (1.f + erff(t * 0.70710678f));
          }
          ep16[lrow * 64 + j * 16 + fr] = f2bf(outv);
        }
        if constexpr (EPI == EPI_EXP) {
          rs += __shfl_xor(rs, 1);
          rs += __shfl_xor(rs, 2);
          rs += __shfl_xor(rs, 4);
          rs += __shfl_xor(rs, 8);
          if (fr == 0) atomicAdd(&lsum[(long)z * M + row], rs);
        }
      }
    }
#pragma unroll
    for (int it = 0; it < 8; ++it) {
      const int lr = it * 8 + (lane >> 3);
      const int ch = (lane & 7) << 3;
      int4 d = *(const int4*)(ep16 + lr * 64 + ch);
      *reinterpret_cast<int4*>(Cg + (long)(rb + lr) * N + cb + ch) = d;
    }
  }
}

// ------- GEMM B: tile 128x128, 4 waves, 256 thr, BK=64 — for N=768 launches (balanced 3/CU) ---
template<int EPI>
__global__ __launch_bounds__(256, 5)
void gemm_bt128(const u16* __restrict__ Aall, const u16* __restrict__ Ball,
                void* __restrict__ Cout,
                int M, int N, int K,
                long sA, long sB, long sC,
                const float* __restrict__ bias,
                const u16* __restrict__ resid,
                float* __restrict__ lsum,
                float scale)
{
  // 32 KB: [0,16K)=As(128x64), [16K,32K)=Bs(128x64); epilogue: 4 x 8 KB wave regions.
  __shared__ __align__(16) char smem[32768];
  u16* As = (u16*)smem;
  u16* Bs = (u16*)(smem + 16384);

  const int z = blockIdx.z;
  const u16* A = Aall + (long)z * sA;
  const u16* B = Ball + (long)z * sB;
  const int bm = blockIdx.x, bn = blockIdx.y;
  const int tid = (int)threadIdx.x;
  const int lane = tid & 63, wv = tid >> 6;   // 4 waves
  const int wr = wv >> 1, wc = wv & 1;        // wave grid 2x2 (64x64 each)

  facc acc[4][4] = {};

  const int srow = tid >> 3;                        // 0..31
  const int scol = (((tid & 7) ^ (srow & 7)) << 3);
  const u16* Abase = A + (long)(bm * 128) * K;
  const u16* Bbase = B + (long)(bn * 128) * K;
  const int fr = lane & 15, g0 = lane >> 4;

  for (int k0 = 0; k0 < K; k0 += 64) {
    __syncthreads();
#pragma unroll
    for (int p = 0; p < 4; ++p) {
      async16(Abase + (long)(p * 32 + srow) * K + k0 + scol, As + (p * 256 + wv * 64) * 8);
      async16(Bbase + (long)(p * 32 + srow) * K + k0 + scol, Bs + (p * 256 + wv * 64) * 8);
    }
    __syncthreads();
#pragma unroll
    for (int h = 0; h < 2; ++h) {
      bfrag af[4], bfv[4];
      const int gh = g0 + h * 4;
#pragma unroll
      for (int i = 0; i < 4; ++i) {
        const int r = wr * 64 + i * 16 + fr;
        af[i] = *(const bfrag*)(As + r * 64 + ((gh ^ (r & 7)) << 3));
      }
#pragma unroll
      for (int j = 0; j < 4; ++j) {
        const int r = wc * 64 + j * 16 + fr;
        bfv[j] = *(const bfrag*)(Bs + r * 64 + ((gh ^ (r & 7)) << 3));
      }
#pragma unroll
      for (int i = 0; i < 4; ++i)
#pragma unroll
        for (int j = 0; j < 4; ++j)
          acc[i][j] = __builtin_amdgcn_mfma_f32_16x16x32_bf16(af[i], bfv[j], acc[i][j], 0, 0, 0);
    }
  }

  __syncthreads();
  const int rb = bm * 128 + wr * 64;
  const int cb = bn * 128 + wc * 64;
  const int quad = lane >> 4;

  if constexpr (EPI == EPI_RES) {
    // bf16 out = acc + bias + bf16 residual; two half-passes of 32 rows x 64 cols fp32
    float* ep32 = (float*)(smem + wv * 8192);
    u16* Cg = (u16*)Cout;
#pragma unroll
    for (int h = 0; h < 2; ++h) {
#pragma unroll
      for (int i2 = 0; i2 < 2; ++i2) {
        const int i = h * 2 + i2;
#pragma unroll
        for (int r = 0; r < 4; ++r) {
          const int lrow = i2 * 16 + quad * 4 + r;
#pragma unroll
          for (int j = 0; j < 4; ++j)
            ep32[lrow * 64 + j * 16 + fr] = acc[i][j][r];
        }
      }
#pragma unroll
      for (int it = 0; it < 8; ++it) {
        const int lr = it * 4 + (lane >> 4);
        const int ch = (lane & 15) << 2;
        float4 d = *(const float4*)(ep32 + lr * 64 + ch);
        const int row = rb + h * 32 + lr;
        const int gcol = cb + ch;
        const long gi = (long)row * N + gcol;
        ushort4 rv = *(const ushort4*)(resid + gi);
        float4 bb = *(const float4*)(bias + gcol);
        ushort4 o;
        o.x = f2bf(d.x + bb.x + bf2f(rv.x));
        o.y = f2bf(d.y + bb.y + bf2f(rv.y));
        o.z = f2bf(d.z + bb.z + bf2f(rv.z));
        o.w = f2bf(d.w + bb.w + bf2f(rv.w));
        *reinterpret_cast<ushort4*>(Cg + gi) = o;
      }
    }
  } else {  // EPI_DIV
    u16* ep16 = (u16*)(smem + wv * 8192);
    u16* Cg = (u16*)Cout + (long)z * sC;
#pragma unroll
    for (int i = 0; i < 4; ++i) {
#pragma unroll
      for (int r = 0; r < 4; ++r) {
        const int lrow = i * 16 + quad * 4 + r;
        const int row = rb + lrow;
        const float inv = 1.f / lsum[(long)z * M + row];
#pragma unroll
        for (int j = 0; j < 4; ++j)
          ep16[lrow * 64 + j * 16 + fr] = f2bf(acc[i][j][r] * inv);
      }
    }
#pragma unroll
    for (int it = 0; it < 8; ++it) {
      const int lr = it * 8 + (lane >> 3);
      const int ch = (lane & 7) << 3;
      int4 d = *(const int4*)(ep16 + lr * 64 + ch);
      *reinterpret_cast<int4*>(Cg + (long)(rb + lr) * N + cb + ch) = d;
    }
  }
}

// ---------------- LayerNorm over rows of 768, bf16 in ----------------
__global__ __launch_bounds__(192) void layernorm_rows(const u16* __restrict__ in,
                                                      const float* __restrict__ gamma,
                                                      const float* __restrict__ beta,
                                                      float* __restrict__ outf,
                                                      u16* __restrict__ outb) {
  const int row = blockIdx.x;
  const int t = threadIdx.x;
  ushort4 uv = ((const ushort4*)(in + (long)row * D_MODEL))[t];
  float v0 = bf2f(uv.x), v1 = bf2f(uv.y), v2 = bf2f(uv.z), v3 = bf2f(uv.w);
  float s1 = v0 + v1 + v2 + v3;
  float s2 = v0 * v0 + v1 * v1 + v2 * v2 + v3 * v3;
#pragma unroll
  for (int o = 32; o; o >>= 1) { s1 += __shfl_xor(s1, o); s2 += __shfl_xor(s2, o); }
  __shared__ float r1[3], r2[3];
  const int wv = t >> 6, ln = t & 63;
  if (ln == 0) { r1[wv] = s1; r2[wv] = s2; }
  __syncthreads();
  s1 = r1[0] + r1[1] + r1[2];
  s2 = r2[0] + r2[1] + r2[2];
  const float mu = s1 * (1.f / 768.f);
  const float var = s2 * (1.f / 768.f) - mu * mu;
  const float rstd = rsqrtf(var + 1e-12f);
  float4 gv = ((const float4*)gamma)[t];
  float4 bv = ((const float4*)beta)[t];
  float o0 = (v0 - mu) * rstd * gv.x + bv.x;
  float o1 = (v1 - mu) * rstd * gv.y + bv.y;
  float o2 = (v2 - mu) * rstd * gv.z + bv.z;
  float o3 = (v3 - mu) * rstd * gv.w + bv.w;
  if (outf) {
    float4 ov = {o0, o1, o2, o3};
    ((float4*)(outf + (long)row * D_MODEL))[t] = ov;
  }
  if (outb) {
    ushort4 ob;
    ob.x = f2bf(o0); ob.y = f2bf(o1); ob.z = f2bf(o2); ob.w = f2bf(o3);
    ((ushort4*)(outb + (long)row * D_MODEL))[t] = ob;
  }
}

// ---------------- workspace layout (bytes), stream-ordered aliasing ----------------
static const size_t OFF_WP   = 0;          // 1179648
static const size_t OFF_W1   = 1179648;    // 2359296
static const size_t OFF_W2   = 3538944;    // 2359296 -> 5898240
static const size_t OFF_LSUM = 5898240;    // 65536
static const size_t OFF_BQKV = 5963776;    // 9216 (pad to 6291456)
static const size_t OFF_QB   = 6291456;    // 25165824  (QB,KB contiguous for EPI_QKV)
static const size_t OFF_KB   = 31457280;   // 25165824
static const size_t OFF_VB   = 56623104;   // 25165824  (now only CTX alias)
static const size_t OFF_VT   = 81788928;   // 25165824  [dead after DIV gemm]
static const size_t OFF_EB   = 106954752;  // 67108864  [dead after DIV gemm]
static const size_t OFF_XB   = 174063616;  // 25165824  [dead after proj gemm]
static const size_t OFF_WQKV = 199229440;  // 3538944 -> 202768384 total
// aliases: CTX=VB; PB=QB; HB=EB head; M1B=QB+KB (50MB); M2B=VT

extern "C" void kernel_launch(void* const* d_in, const int* in_sizes, int n_in,
                              void* d_out, int out_size, void* d_ws, size_t ws_size,
                              hipStream_t stream) {
  const float* x   = (const float*)d_in[0];
  const float* Wq  = (const float*)d_in[1];
  const float* bq  = (const float*)d_in[2];
  const float* Wk  = (const float*)d_in[3];
  const float* bk  = (const float*)d_in[4];
  const float* Wv  = (const float*)d_in[5];
  const float* bv  = (const float*)d_in[6];
  const float* Wp  = (const float*)d_in[7];
  const float* bp  = (const float*)d_in[8];
  const float* g1  = (const float*)d_in[9];
  const float* be1 = (const float*)d_in[10];
  const float* W1  = (const float*)d_in[11];
  const float* b1  = (const float*)d_in[12];
  const float* W2  = (const float*)d_in[13];
  const float* b2  = (const float*)d_in[14];
  const float* g2  = (const float*)d_in[15];
  const float* be2 = (const float*)d_in[16];

  char* ws = (char*)d_ws;
  u16*   WPB  = (u16*)(ws + OFF_WP);
  u16*   W1B  = (u16*)(ws + OFF_W1);
  u16*   W2B  = (u16*)(ws + OFF_W2);
  float* LSUM = (float*)(ws + OFF_LSUM);
  float* BQKV = (float*)(ws + OFF_BQKV);
  u16*   QB   = (u16*)(ws + OFF_QB);
  u16*   KB   = (u16*)(ws + OFF_KB);
  u16*   VT   = (u16*)(ws + OFF_VT);
  u16*   EB   = (u16*)(ws + OFF_EB);
  u16*   XB   = (u16*)(ws + OFF_XB);
  u16*   WQKV = (u16*)(ws + OFF_WQKV);
  // aliases (stream-ordered lifetimes)
  u16*   CTX  = (u16*)(ws + OFF_VB);   // VB region (V never materialized untransposed)
  u16*   PB   = (u16*)(ws + OFF_QB);   // after EXP frees QB
  u16*   HB   = (u16*)(ws + OFF_EB);   // after DIV frees EB
  u16*   M1B  = (u16*)(ws + OFF_QB);   // after LN1 frees PB; KB free after EXP
  u16*   M2B  = (u16*)(ws + OFF_VT);   // after DIV frees VT

  dim3 blk(256), blkg(512), blkl(192);

  // all f32->bf16 conversions + bias concat, one kernel
  cvt_all<<<dim3(16899), blk, 0, stream>>>(x, Wq, Wk, Wv, Wp, W1, W2, bq, bk, bv,
                                           XB, WQKV, WPB, W1B, W2B, BQKV);
  hipMemsetAsync(LSUM, 0, NROWS * sizeof(float), stream);

  // fused QKV projection: Q,K -> QB|KB (row-major), V -> VT (transposed, fused)
  gemm_bt<EPI_QKV><<<dim3(128, 9, 1), blkg, 0, stream>>>(XB, WQKV, QB,
      NROWS, 3 * D_MODEL, D_MODEL, 0, 0, 0, BQKV, VT, nullptr, 0.f);

  // scores: E = exp(Q K^T / sqrt(D)), row sums into LSUM
  const float sc = 1.0f / sqrtf((float)D_MODEL);
  gemm_bt<EPI_EXP><<<dim3(16, 8, 8), blkg, 0, stream>>>(QB, KB, EB,
      SEQLEN, SEQLEN, D_MODEL,
      (long)SEQLEN * D_MODEL, (long)SEQLEN * D_MODEL, (long)SEQLEN * SEQLEN,
      nullptr, nullptr, LSUM, sc);
  // context: Ctx = (E V) / lsum   (128x128 tiles -> 768 blocks, 3/CU balanced)
  gemm_bt128<EPI_DIV><<<dim3(16, 6, 8), blk, 0, stream>>>(EB, VT, CTX,
      SEQLEN, D_MODEL, SEQLEN,
      (long)SEQLEN * SEQLEN, (long)D_MODEL * SEQLEN, (long)SEQLEN * D_MODEL,
      nullptr, nullptr, LSUM, 0.f);
  // proj + residual (bf16): PB = bf16(x + Ctx Wp^T + bp)
  gemm_bt128<EPI_RES><<<dim3(128, 6, 1), blk, 0, stream>>>(CTX, WPB, PB,
      NROWS, D_MODEL, D_MODEL, 0, 0, 0, bp, XB, nullptr, 0.f);
  // LN1 -> HB (bf16)
  layernorm_rows<<<dim3(NROWS), blkl, 0, stream>>>(PB, g1, be1, nullptr, HB);
  // MLP1 + exact gelu -> M1B (bf16)
  gemm_bt<EPI_GELU><<<dim3(128, 6, 1), blkg, 0, stream>>>(HB, W1B, M1B,
      NROWS, D_HID, D_MODEL, 0, 0, 0, b1, nullptr, nullptr, 0.f);
  // MLP2 + residual (bf16): M2B = bf16(h + M1 W2^T + b2)
  gemm_bt128<EPI_RES><<<dim3(128, 6, 1), blk, 0, stream>>>(M1B, W2B, M2B,
      NROWS, D_MODEL, D_HID, 0, 0, 0, b2, HB, nullptr, 0.f);
  // LN2 -> d_out (fp32)
  layernorm_rows<<<dim3(NROWS), blkl, 0, stream>>>(M2B, g2, be2, (float*)d_out, nullptr);

  (void)in_sizes; (void)n_in; (void)out_size; (void)ws_size;
}

// Round 8
// 482.026 us; speedup vs baseline: 1.3817x; 1.3817x over previous
//
#include <hip/hip_runtime.h>
#include <math.h>

#define D_MODEL 768
#define D_HID   1536
#define N_BATCH 8
#define SEQLEN  2048
#define NROWS   (N_BATCH*SEQLEN)   // 16384

typedef unsigned short u16;
typedef __attribute__((ext_vector_type(8))) short bfrag;   // 8 x bf16 (4 VGPRs)
typedef __attribute__((ext_vector_type(4))) float facc;    // 4 x fp32 acc

__device__ __forceinline__ u16 f2bf(float f) {
  unsigned u = __float_as_uint(f);
  u += 0x7fffu + ((u >> 16) & 1u);
  return (u16)(u >> 16);
}
__device__ __forceinline__ float bf2f(u16 u) {
  return __uint_as_float((unsigned)u << 16);
}

__device__ __forceinline__ void async16(const void* g, void* l) {
  __builtin_amdgcn_global_load_lds((const __attribute__((address_space(1))) void*)g,
                                   (__attribute__((address_space(3))) void*)l,
                                   16, 0, 0);
}

// ---------------- fused f32->bf16 conversion of all operands + bias concat ----------------
__global__ __launch_bounds__(256) void cvt_all(
    const float* __restrict__ x,  const float* __restrict__ Wq,
    const float* __restrict__ Wk, const float* __restrict__ Wv,
    const float* __restrict__ Wp, const float* __restrict__ W1,
    const float* __restrict__ W2, const float* __restrict__ bq,
    const float* __restrict__ bk, const float* __restrict__ bv,
    u16* __restrict__ XB, u16* __restrict__ WQKV, u16* __restrict__ WPB,
    u16* __restrict__ W1B, u16* __restrict__ W2B, float* __restrict__ BQKV) {
  long i = (long)blockIdx.x * 256 + threadIdx.x;
  const float* src; u16* dst; long off;
  if      (i < 3145728) { src = x;  dst = XB;             off = i; }
  else if (i < 3293184) { src = Wq; dst = WQKV;           off = i - 3145728; }
  else if (i < 3440640) { src = Wk; dst = WQKV + 589824;  off = i - 3293184; }
  else if (i < 3588096) { src = Wv; dst = WQKV + 1179648; off = i - 3440640; }
  else if (i < 3735552) { src = Wp; dst = WPB;            off = i - 3588096; }
  else if (i < 4030464) { src = W1; dst = W1B;            off = i - 3735552; }
  else if (i < 4325376) { src = W2; dst = W2B;            off = i - 4030464; }
  else if (i < 4325952) {
    long j = i - 4325376;   // 0..575 -> BQKV[j] (f4), concatenated bq|bk|bv
    const float* s = (j < 192) ? bq : (j < 384) ? bk : bv;
    long o = (j < 192) ? j : (j < 384) ? j - 192 : j - 384;
    ((float4*)BQKV)[j] = ((const float4*)s)[o];
    return;
  } else return;
  float4 v = ((const float4*)src)[off];
  ushort4 o4;
  o4.x = f2bf(v.x); o4.y = f2bf(v.y); o4.z = f2bf(v.z); o4.w = f2bf(v.w);
  *reinterpret_cast<ushort4*>(dst + off * 4) = o4;
}

// ------- GEMM A: C[M,N] = A[M,K]*B[N,K]^T, tile 128x256, BK=64, 8 waves, 16x16x32 MFMA -------
enum { EPI_EXP = 1, EPI_DIV = 2, EPI_GELU = 4, EPI_QKV = 5, EPI_RES = 6 };

template<int EPI>
__global__ __launch_bounds__(512, 4)
void gemm_bt(const u16* __restrict__ Aall, const u16* __restrict__ Ball,
             void* __restrict__ Cout,
             int M, int N, int K,
             long sA, long sB, long sC,
             const float* __restrict__ bias,
             const u16* __restrict__ resid,   // EPI_RES: residual; EPI_QKV: VT out
             float* __restrict__ lsum,
             float scale)
{
  // 64 KB: [0,16K)=As(128x64), [16K,48K)=Bs(256x64) during K-loop;
  // epilogue (after barrier): 8 x 8 KB per-wave regions.
  __shared__ __align__(16) char smem[65536];
  u16* As = (u16*)smem;
  u16* Bs = (u16*)(smem + 16384);

  const int z = blockIdx.z;
  const u16* A = Aall + (long)z * sA;
  const u16* B = Ball + (long)z * sB;
  const int bm = blockIdx.x, bn = blockIdx.y;
  const int tid = (int)threadIdx.x;
  const int lane = tid & 63, wv = tid >> 6;          // 8 waves
  const int wr = wv >> 2, wc = wv & 3;               // wave grid 2x4 (64x64 each)

  facc acc[4][4] = {};

  const int srow = tid >> 3;                          // 0..63
  const int scol = (((tid & 7) ^ (srow & 7)) << 3);   // XOR-swizzled source elem offset
  const u16* Abase = A + (long)(bm * 128) * K;
  const u16* Bbase = B + (long)(bn * 256) * K;

  const int fr = lane & 15;
  const int g0 = lane >> 4;                           // base k-chunk (0..3)

  for (int k0 = 0; k0 < K; k0 += 64) {
    __syncthreads();
#pragma unroll
    for (int p = 0; p < 2; ++p)    // A: 128 rows
      async16(Abase + (long)(p * 64 + srow) * K + k0 + scol, As + (p * 512 + wv * 64) * 8);
#pragma unroll
    for (int p = 0; p < 4; ++p)    // B: 256 rows
      async16(Bbase + (long)(p * 64 + srow) * K + k0 + scol, Bs + (p * 512 + wv * 64) * 8);
    __syncthreads();
#pragma unroll
    for (int h = 0; h < 2; ++h) {
      bfrag af[4], bfv[4];
      const int gh = g0 + h * 4;
#pragma unroll
      for (int i = 0; i < 4; ++i) {
        const int r = wr * 64 + i * 16 + fr;
        af[i] = *(const bfrag*)(As + r * 64 + ((gh ^ (r & 7)) << 3));
      }
#pragma unroll
      for (int j = 0; j < 4; ++j) {
        const int r = wc * 64 + j * 16 + fr;
        bfv[j] = *(const bfrag*)(Bs + r * 64 + ((gh ^ (r & 7)) << 3));
      }
#pragma unroll
      for (int i = 0; i < 4; ++i)
#pragma unroll
        for (int j = 0; j < 4; ++j)
          acc[i][j] = __builtin_amdgcn_mfma_f32_16x16x32_bf16(af[i], bfv[j], acc[i][j], 0, 0, 0);
    }
  }

  // ---- epilogue ----  16x16 C/D layout: col = lane&15, row = (lane>>4)*4 + reg
  __syncthreads();   // done reading As/Bs; smem becomes 8 x 8KB wave staging
  const int rb = bm * 128 + wr * 64;
  const int cb = bn * 256 + wc * 64;
  const int quad = lane >> 4;

  if constexpr (EPI == EPI_QKV) {
    const int c64 = bn * 4 + wc;         // 0..35
    const int which = c64 / 12;          // 0=Q,1=K,2=V
    float bj[4];
#pragma unroll
    for (int j = 0; j < 4; ++j) bj[j] = bias[cb + j * 16 + fr];
    if (which == 2) {
      // V: direct transposed register stores -> VT[z][dim][seq]
      u16* VT_ = (u16*)resid;
      const int zb = rb >> 11;
      const int seqb = (rb & 2047) + quad * 4;
      const int dimb = (c64 - 24) * 64;
#pragma unroll
      for (int i = 0; i < 4; ++i) {
#pragma unroll
        for (int j = 0; j < 4; ++j) {
          const int dim = dimb + j * 16 + fr;
          ushort4 o;
          o.x = f2bf(acc[i][j][0] + bj[j]);
          o.y = f2bf(acc[i][j][1] + bj[j]);
          o.z = f2bf(acc[i][j][2] + bj[j]);
          o.w = f2bf(acc[i][j][3] + bj[j]);
          *reinterpret_cast<ushort4*>(VT_ + (long)zb * D_MODEL * SEQLEN +
                                      (long)dim * SEQLEN + seqb + i * 16) = o;
        }
      }
      return;
    }
    // Q/K: stage in per-wave LDS then coalesced int4 stores
    u16* ep16 = (u16*)(smem + wv * 8192);
    u16* Cg = (u16*)Cout + (long)which * NROWS * D_MODEL;
    const int cbo = (c64 - which * 12) * 64;
#pragma unroll
    for (int i = 0; i < 4; ++i)
#pragma unroll
      for (int r = 0; r < 4; ++r) {
        const int lrow = i * 16 + quad * 4 + r;
#pragma unroll
        for (int j = 0; j < 4; ++j)
          ep16[lrow * 64 + j * 16 + fr] = f2bf(acc[i][j][r] + bj[j]);
      }
#pragma unroll
    for (int it = 0; it < 8; ++it) {
      const int lr = it * 8 + (lane >> 3);
      const int ch = (lane & 7) << 3;
      int4 d = *(const int4*)(ep16 + lr * 64 + ch);
      *reinterpret_cast<int4*>(Cg + (long)(rb + lr) * D_MODEL + cbo + ch) = d;
    }
  } else {
    // EXP / GELU: bf16 out via staged LDS
    u16* ep16 = (u16*)(smem + wv * 8192);
    u16* Cg = (u16*)Cout + (long)z * sC;
    float bj[4];
    if constexpr (EPI == EPI_GELU) {
#pragma unroll
      for (int j = 0; j < 4; ++j) bj[j] = bias[cb + j * 16 + fr];
    }
#pragma unroll
    for (int i = 0; i < 4; ++i) {
#pragma unroll
      for (int r = 0; r < 4; ++r) {
        const int lrow = i * 16 + quad * 4 + r;
        const int row = rb + lrow;
        float rs = 0.f;
#pragma unroll
        for (int j = 0; j < 4; ++j) {
          float v = acc[i][j][r];
          float outv;
          if constexpr (EPI == EPI_EXP) {
            outv = __expf(v * scale);
            rs += outv;
          } else { // EPI_GELU
            float t = v + bj[j];
            outv = 0.5f * t * (1.f + erff(t * 0.70710678f));
          }
          ep16[lrow * 64 + j * 16 + fr] = f2bf(outv);
        }
        if constexpr (EPI == EPI_EXP) {
          rs += __shfl_xor(rs, 1);
          rs += __shfl_xor(rs, 2);
          rs += __shfl_xor(rs, 4);
          rs += __shfl_xor(rs, 8);
          if (fr == 0) atomicAdd(&lsum[(long)z * M + row], rs);
        }
      }
    }
#pragma unroll
    for (int it = 0; it < 8; ++it) {
      const int lr = it * 8 + (lane >> 3);
      const int ch = (lane & 7) << 3;
      int4 d = *(const int4*)(ep16 + lr * 64 + ch);
      *reinterpret_cast<int4*>(Cg + (long)(rb + lr) * N + cb + ch) = d;
    }
  }
}

// ------- GEMM B: tile 128x128, 4 waves, 256 thr, BK=64 — for N=768 launches (balanced 3/CU) ---
// NOTE launch_bounds (256,4): VGPR cap 128 >= ~92 needed. (256,5) capped at ~102->48-granule
// and spilled the 64-reg accumulator to scratch (r7: 345 MB WRITE/dispatch, 2x regression).
template<int EPI>
__global__ __launch_bounds__(256, 4)
void gemm_bt128(const u16* __restrict__ Aall, const u16* __restrict__ Ball,
                void* __restrict__ Cout,
                int M, int N, int K,
                long sA, long sB, long sC,
                const float* __restrict__ bias,
                const u16* __restrict__ resid,
                float* __restrict__ lsum,
                float scale)
{
  // 32 KB: [0,16K)=As(128x64), [16K,32K)=Bs(128x64); epilogue: 4 x 8 KB wave regions.
  __shared__ __align__(16) char smem[32768];
  u16* As = (u16*)smem;
  u16* Bs = (u16*)(smem + 16384);

  const int z = blockIdx.z;
  const u16* A = Aall + (long)z * sA;
  const u16* B = Ball + (long)z * sB;
  const int bm = blockIdx.x, bn = blockIdx.y;
  const int tid = (int)threadIdx.x;
  const int lane = tid & 63, wv = tid >> 6;   // 4 waves
  const int wr = wv >> 1, wc = wv & 1;        // wave grid 2x2 (64x64 each)

  facc acc[4][4] = {};

  const int srow = tid >> 3;                        // 0..31
  const int scol = (((tid & 7) ^ (srow & 7)) << 3);
  const u16* Abase = A + (long)(bm * 128) * K;
  const u16* Bbase = B + (long)(bn * 128) * K;
  const int fr = lane & 15, g0 = lane >> 4;

  for (int k0 = 0; k0 < K; k0 += 64) {
    __syncthreads();
#pragma unroll
    for (int p = 0; p < 4; ++p) {
      async16(Abase + (long)(p * 32 + srow) * K + k0 + scol, As + (p * 256 + wv * 64) * 8);
      async16(Bbase + (long)(p * 32 + srow) * K + k0 + scol, Bs + (p * 256 + wv * 64) * 8);
    }
    __syncthreads();
#pragma unroll
    for (int h = 0; h < 2; ++h) {
      bfrag af[4], bfv[4];
      const int gh = g0 + h * 4;
#pragma unroll
      for (int i = 0; i < 4; ++i) {
        const int r = wr * 64 + i * 16 + fr;
        af[i] = *(const bfrag*)(As + r * 64 + ((gh ^ (r & 7)) << 3));
      }
#pragma unroll
      for (int j = 0; j < 4; ++j) {
        const int r = wc * 64 + j * 16 + fr;
        bfv[j] = *(const bfrag*)(Bs + r * 64 + ((gh ^ (r & 7)) << 3));
      }
#pragma unroll
      for (int i = 0; i < 4; ++i)
#pragma unroll
        for (int j = 0; j < 4; ++j)
          acc[i][j] = __builtin_amdgcn_mfma_f32_16x16x32_bf16(af[i], bfv[j], acc[i][j], 0, 0, 0);
    }
  }

  __syncthreads();
  const int rb = bm * 128 + wr * 64;
  const int cb = bn * 128 + wc * 64;
  const int quad = lane >> 4;

  if constexpr (EPI == EPI_RES) {
    // bf16 out = acc + bias + bf16 residual; two half-passes of 32 rows x 64 cols fp32
    float* ep32 = (float*)(smem + wv * 8192);
    u16* Cg = (u16*)Cout;
#pragma unroll
    for (int h = 0; h < 2; ++h) {
#pragma unroll
      for (int i2 = 0; i2 < 2; ++i2) {
        const int i = h * 2 + i2;
#pragma unroll
        for (int r = 0; r < 4; ++r) {
          const int lrow = i2 * 16 + quad * 4 + r;
#pragma unroll
          for (int j = 0; j < 4; ++j)
            ep32[lrow * 64 + j * 16 + fr] = acc[i][j][r];
        }
      }
#pragma unroll
      for (int it = 0; it < 8; ++it) {
        const int lr = it * 4 + (lane >> 4);
        const int ch = (lane & 15) << 2;
        float4 d = *(const float4*)(ep32 + lr * 64 + ch);
        const int row = rb + h * 32 + lr;
        const int gcol = cb + ch;
        const long gi = (long)row * N + gcol;
        ushort4 rv = *(const ushort4*)(resid + gi);
        float4 bb = *(const float4*)(bias + gcol);
        ushort4 o;
        o.x = f2bf(d.x + bb.x + bf2f(rv.x));
        o.y = f2bf(d.y + bb.y + bf2f(rv.y));
        o.z = f2bf(d.z + bb.z + bf2f(rv.z));
        o.w = f2bf(d.w + bb.w + bf2f(rv.w));
        *reinterpret_cast<ushort4*>(Cg + gi) = o;
      }
    }
  } else {  // EPI_DIV
    u16* ep16 = (u16*)(smem + wv * 8192);
    u16* Cg = (u16*)Cout + (long)z * sC;
#pragma unroll
    for (int i = 0; i < 4; ++i) {
#pragma unroll
      for (int r = 0; r < 4; ++r) {
        const int lrow = i * 16 + quad * 4 + r;
        const int row = rb + lrow;
        const float inv = 1.f / lsum[(long)z * M + row];
#pragma unroll
        for (int j = 0; j < 4; ++j)
          ep16[lrow * 64 + j * 16 + fr] = f2bf(acc[i][j][r] * inv);
      }
    }
#pragma unroll
    for (int it = 0; it < 8; ++it) {
      const int lr = it * 8 + (lane >> 3);
      const int ch = (lane & 7) << 3;
      int4 d = *(const int4*)(ep16 + lr * 64 + ch);
      *reinterpret_cast<int4*>(Cg + (long)(rb + lr) * N + cb + ch) = d;
    }
  }
}

// ---------------- LayerNorm over rows of 768, bf16 in ----------------
__global__ __launch_bounds__(192) void layernorm_rows(const u16* __restrict__ in,
                                                      const float* __restrict__ gamma,
                                                      const float* __restrict__ beta,
                                                      float* __restrict__ outf,
                                                      u16* __restrict__ outb) {
  const int row = blockIdx.x;
  const int t = threadIdx.x;
  ushort4 uv = ((const ushort4*)(in + (long)row * D_MODEL))[t];
  float v0 = bf2f(uv.x), v1 = bf2f(uv.y), v2 = bf2f(uv.z), v3 = bf2f(uv.w);
  float s1 = v0 + v1 + v2 + v3;
  float s2 = v0 * v0 + v1 * v1 + v2 * v2 + v3 * v3;
#pragma unroll
  for (int o = 32; o; o >>= 1) { s1 += __shfl_xor(s1, o); s2 += __shfl_xor(s2, o); }
  __shared__ float r1[3], r2[3];
  const int wv = t >> 6, ln = t & 63;
  if (ln == 0) { r1[wv] = s1; r2[wv] = s2; }
  __syncthreads();
  s1 = r1[0] + r1[1] + r1[2];
  s2 = r2[0] + r2[1] + r2[2];
  const float mu = s1 * (1.f / 768.f);
  const float var = s2 * (1.f / 768.f) - mu * mu;
  const float rstd = rsqrtf(var + 1e-12f);
  float4 gv = ((const float4*)gamma)[t];
  float4 bv = ((const float4*)beta)[t];
  float o0 = (v0 - mu) * rstd * gv.x + bv.x;
  float o1 = (v1 - mu) * rstd * gv.y + bv.y;
  float o2 = (v2 - mu) * rstd * gv.z + bv.z;
  float o3 = (v3 - mu) * rstd * gv.w + bv.w;
  if (outf) {
    float4 ov = {o0, o1, o2, o3};
    ((float4*)(outf + (long)row * D_MODEL))[t] = ov;
  }
  if (outb) {
    ushort4 ob;
    ob.x = f2bf(o0); ob.y = f2bf(o1); ob.z = f2bf(o2); ob.w = f2bf(o3);
    ((ushort4*)(outb + (long)row * D_MODEL))[t] = ob;
  }
}

// ---------------- workspace layout (bytes), stream-ordered aliasing ----------------
static const size_t OFF_WP   = 0;          // 1179648
static const size_t OFF_W1   = 1179648;    // 2359296
static const size_t OFF_W2   = 3538944;    // 2359296 -> 5898240
static const size_t OFF_LSUM = 5898240;    // 65536
static const size_t OFF_BQKV = 5963776;    // 9216 (pad to 6291456)
static const size_t OFF_QB   = 6291456;    // 25165824  (QB,KB contiguous for EPI_QKV)
static const size_t OFF_KB   = 31457280;   // 25165824
static const size_t OFF_VB   = 56623104;   // 25165824  (only CTX alias now)
static const size_t OFF_VT   = 81788928;   // 25165824  [dead after DIV gemm]
static const size_t OFF_EB   = 106954752;  // 67108864  [dead after DIV gemm]
static const size_t OFF_XB   = 174063616;  // 25165824  [dead after proj gemm]
static const size_t OFF_WQKV = 199229440;  // 3538944 -> 202768384 total
// aliases: CTX=VB; PB=QB; HB=EB head; M1B=QB+KB (50MB); M2B=VT

extern "C" void kernel_launch(void* const* d_in, const int* in_sizes, int n_in,
                              void* d_out, int out_size, void* d_ws, size_t ws_size,
                              hipStream_t stream) {
  const float* x   = (const float*)d_in[0];
  const float* Wq  = (const float*)d_in[1];
  const float* bq  = (const float*)d_in[2];
  const float* Wk  = (const float*)d_in[3];
  const float* bk  = (const float*)d_in[4];
  const float* Wv  = (const float*)d_in[5];
  const float* bv  = (const float*)d_in[6];
  const float* Wp  = (const float*)d_in[7];
  const float* bp  = (const float*)d_in[8];
  const float* g1  = (const float*)d_in[9];
  const float* be1 = (const float*)d_in[10];
  const float* W1  = (const float*)d_in[11];
  const float* b1  = (const float*)d_in[12];
  const float* W2  = (const float*)d_in[13];
  const float* b2  = (const float*)d_in[14];
  const float* g2  = (const float*)d_in[15];
  const float* be2 = (const float*)d_in[16];

  char* ws = (char*)d_ws;
  u16*   WPB  = (u16*)(ws + OFF_WP);
  u16*   W1B  = (u16*)(ws + OFF_W1);
  u16*   W2B  = (u16*)(ws + OFF_W2);
  float* LSUM = (float*)(ws + OFF_LSUM);
  float* BQKV = (float*)(ws + OFF_BQKV);
  u16*   QB   = (u16*)(ws + OFF_QB);
  u16*   KB   = (u16*)(ws + OFF_KB);
  u16*   VT   = (u16*)(ws + OFF_VT);
  u16*   EB   = (u16*)(ws + OFF_EB);
  u16*   XB   = (u16*)(ws + OFF_XB);
  u16*   WQKV = (u16*)(ws + OFF_WQKV);
  // aliases (stream-ordered lifetimes)
  u16*   CTX  = (u16*)(ws + OFF_VB);
  u16*   PB   = (u16*)(ws + OFF_QB);
  u16*   HB   = (u16*)(ws + OFF_EB);
  u16*   M1B  = (u16*)(ws + OFF_QB);
  u16*   M2B  = (u16*)(ws + OFF_VT);

  dim3 blk(256), blkg(512), blkl(192);

  // all f32->bf16 conversions + bias concat, one kernel
  cvt_all<<<dim3(16899), blk, 0, stream>>>(x, Wq, Wk, Wv, Wp, W1, W2, bq, bk, bv,
                                           XB, WQKV, WPB, W1B, W2B, BQKV);
  hipMemsetAsync(LSUM, 0, NROWS * sizeof(float), stream);

  // fused QKV projection: Q,K -> QB|KB (row-major), V -> VT (transposed, fused)
  gemm_bt<EPI_QKV><<<dim3(128, 9, 1), blkg, 0, stream>>>(XB, WQKV, QB,
      NROWS, 3 * D_MODEL, D_MODEL, 0, 0, 0, BQKV, VT, nullptr, 0.f);

  // scores: E = exp(Q K^T / sqrt(D)), row sums into LSUM
  const float sc = 1.0f / sqrtf((float)D_MODEL);
  gemm_bt<EPI_EXP><<<dim3(16, 8, 8), blkg, 0, stream>>>(QB, KB, EB,
      SEQLEN, SEQLEN, D_MODEL,
      (long)SEQLEN * D_MODEL, (long)SEQLEN * D_MODEL, (long)SEQLEN * SEQLEN,
      nullptr, nullptr, LSUM, sc);
  // context: Ctx = (E V) / lsum   (128x128 tiles -> 768 blocks, 3/CU balanced)
  gemm_bt128<EPI_DIV><<<dim3(16, 6, 8), blk, 0, stream>>>(EB, VT, CTX,
      SEQLEN, D_MODEL, SEQLEN,
      (long)SEQLEN * SEQLEN, (long)D_MODEL * SEQLEN, (long)SEQLEN * D_MODEL,
      nullptr, nullptr, LSUM, 0.f);
  // proj + residual (bf16): PB = bf16(x + Ctx Wp^T + bp)
  gemm_bt128<EPI_RES><<<dim3(128, 6, 1), blk, 0, stream>>>(CTX, WPB, PB,
      NROWS, D_MODEL, D_MODEL, 0, 0, 0, bp, XB, nullptr, 0.f);
  // LN1 -> HB (bf16)
  layernorm_rows<<<dim3(NROWS), blkl, 0, stream>>>(PB, g1, be1, nullptr, HB);
  // MLP1 + exact gelu -> M1B (bf16)
  gemm_bt<EPI_GELU><<<dim3(128, 6, 1), blkg, 0, stream>>>(HB, W1B, M1B,
      NROWS, D_HID, D_MODEL, 0, 0, 0, b1, nullptr, nullptr, 0.f);
  // MLP2 + residual (bf16): M2B = bf16(h + M1 W2^T + b2)
  gemm_bt128<EPI_RES><<<dim3(128, 6, 1), blk, 0, stream>>>(M1B, W2B, M2B,
      NROWS, D_MODEL, D_HID, 0, 0, 0, b2, HB, nullptr, 0.f);
  // LN2 -> d_out (fp32)
  layernorm_rows<<<dim3(NROWS), blkl, 0, stream>>>(M2B, g2, be2, (float*)d_out, nullptr);

  (void)in_sizes; (void)n_in; (void)out_size; (void)ws_size;
}

// Round 9
// 471.286 us; speedup vs baseline: 1.4132x; 1.0228x over previous
//
#include <hip/hip_runtime.h>
#include <math.h>

#define D_MODEL 768
#define D_HID   1536
#define N_BATCH 8
#define SEQLEN  2048
#define NROWS   (N_BATCH*SEQLEN)   // 16384

typedef unsigned short u16;
typedef unsigned char  u8;
typedef __attribute__((ext_vector_type(8))) short bfrag;   // 8 x bf16 (4 VGPRs)
typedef __attribute__((ext_vector_type(4))) float facc;    // 4 x fp32 acc

__device__ __forceinline__ u16 f2bf(float f) {
  unsigned u = __float_as_uint(f);
  u += 0x7fffu + ((u >> 16) & 1u);
  return (u16)(u >> 16);
}
__device__ __forceinline__ float bf2f(u16 u) {
  return __uint_as_float((unsigned)u << 16);
}
__device__ __forceinline__ u8 f2fp8(float f) {   // OCP e4m3 on gfx950
  return (u8)(__builtin_amdgcn_cvt_pk_fp8_f32(f, f, 0, 0) & 0xff);
}

__device__ __forceinline__ void async16(const void* g, void* l) {
  __builtin_amdgcn_global_load_lds((const __attribute__((address_space(1))) void*)g,
                                   (__attribute__((address_space(3))) void*)l,
                                   16, 0, 0);
}

// ------- fused f32->bf16 conversion of all operands + bias concat + LSUM zero -------
__global__ __launch_bounds__(256) void cvt_all(
    const float* __restrict__ x,  const float* __restrict__ Wq,
    const float* __restrict__ Wk, const float* __restrict__ Wv,
    const float* __restrict__ Wp, const float* __restrict__ W1,
    const float* __restrict__ W2, const float* __restrict__ bq,
    const float* __restrict__ bk, const float* __restrict__ bv,
    u16* __restrict__ XB, u16* __restrict__ WQKV, u16* __restrict__ WPB,
    u16* __restrict__ W1B, u16* __restrict__ W2B, float* __restrict__ BQKV,
    float* __restrict__ LSUM) {
  long i = (long)blockIdx.x * 256 + threadIdx.x;
  const float* src; u16* dst; long off;
  if      (i < 3145728) { src = x;  dst = XB;             off = i; }
  else if (i < 3293184) { src = Wq; dst = WQKV;           off = i - 3145728; }
  else if (i < 3440640) { src = Wk; dst = WQKV + 589824;  off = i - 3293184; }
  else if (i < 3588096) { src = Wv; dst = WQKV + 1179648; off = i - 3440640; }
  else if (i < 3735552) { src = Wp; dst = WPB;            off = i - 3588096; }
  else if (i < 4030464) { src = W1; dst = W1B;            off = i - 3735552; }
  else if (i < 4325376) { src = W2; dst = W2B;            off = i - 4030464; }
  else if (i < 4325952) {
    long j = i - 4325376;   // 0..575 -> BQKV[j] (f4), concatenated bq|bk|bv
    const float* s = (j < 192) ? bq : (j < 384) ? bk : bv;
    long o = (j < 192) ? j : (j < 384) ? j - 192 : j - 384;
    ((float4*)BQKV)[j] = ((const float4*)s)[o];
    return;
  } else if (i < 4330048) {
    float4 zz = {0.f, 0.f, 0.f, 0.f};
    ((float4*)LSUM)[i - 4325952] = zz;
    return;
  } else return;
  float4 v = ((const float4*)src)[off];
  ushort4 o4;
  o4.x = f2bf(v.x); o4.y = f2bf(v.y); o4.z = f2bf(v.z); o4.w = f2bf(v.w);
  *reinterpret_cast<ushort4*>(dst + off * 4) = o4;
}

// ------- GEMM A (bf16): C = A*B^T, tile 128x256, BK=64, 8 waves, 16x16x32 MFMA -------
enum { EPI_EXP = 1, EPI_DIV = 2, EPI_GELU = 4, EPI_QKV = 5, EPI_RES = 6 };

template<int EPI>
__global__ __launch_bounds__(512, 4)
void gemm_bt(const u16* __restrict__ Aall, const u16* __restrict__ Ball,
             void* __restrict__ Cout,
             int M, int N, int K,
             long sA, long sB, long sC,
             const float* __restrict__ bias,
             const u16* __restrict__ resid,   // EPI_RES: residual; EPI_QKV: VT out (fp8)
             float* __restrict__ lsum,
             float scale)
{
  __shared__ __align__(16) char smem[65536];
  u16* As = (u16*)smem;
  u16* Bs = (u16*)(smem + 16384);

  const int z = blockIdx.z;
  const u16* A = Aall + (long)z * sA;
  const u16* B = Ball + (long)z * sB;
  const int bm = blockIdx.x, bn = blockIdx.y;
  const int tid = (int)threadIdx.x;
  const int lane = tid & 63, wv = tid >> 6;
  const int wr = wv >> 2, wc = wv & 3;               // wave grid 2x4 (64x64 each)

  facc acc[4][4] = {};

  const int srow = tid >> 3;                          // 0..63
  const int scol = (((tid & 7) ^ (srow & 7)) << 3);   // XOR-swizzled source elem offset
  const u16* Abase = A + (long)(bm * 128) * K;
  const u16* Bbase = B + (long)(bn * 256) * K;

  const int fr = lane & 15;
  const int g0 = lane >> 4;

  for (int k0 = 0; k0 < K; k0 += 64) {
    __syncthreads();
#pragma unroll
    for (int p = 0; p < 2; ++p)
      async16(Abase + (long)(p * 64 + srow) * K + k0 + scol, As + (p * 512 + wv * 64) * 8);
#pragma unroll
    for (int p = 0; p < 4; ++p)
      async16(Bbase + (long)(p * 64 + srow) * K + k0 + scol, Bs + (p * 512 + wv * 64) * 8);
    __syncthreads();
#pragma unroll
    for (int h = 0; h < 2; ++h) {
      bfrag af[4], bfv[4];
      const int gh = g0 + h * 4;
#pragma unroll
      for (int i = 0; i < 4; ++i) {
        const int r = wr * 64 + i * 16 + fr;
        af[i] = *(const bfrag*)(As + r * 64 + ((gh ^ (r & 7)) << 3));
      }
#pragma unroll
      for (int j = 0; j < 4; ++j) {
        const int r = wc * 64 + j * 16 + fr;
        bfv[j] = *(const bfrag*)(Bs + r * 64 + ((gh ^ (r & 7)) << 3));
      }
#pragma unroll
      for (int i = 0; i < 4; ++i)
#pragma unroll
        for (int j = 0; j < 4; ++j)
          acc[i][j] = __builtin_amdgcn_mfma_f32_16x16x32_bf16(af[i], bfv[j], acc[i][j], 0, 0, 0);
    }
  }

  // ---- epilogue ---- 16x16 C/D layout: col = lane&15, row = (lane>>4)*4 + reg
  __syncthreads();
  const int rb = bm * 128 + wr * 64;
  const int cb = bn * 256 + wc * 64;
  const int quad = lane >> 4;

  if constexpr (EPI == EPI_QKV) {
    // fp8 outputs: Q,K row-major; V transposed
    const int c64 = bn * 4 + wc;         // 0..35
    const int which = c64 / 12;          // 0=Q,1=K,2=V
    float bj[4];
#pragma unroll
    for (int j = 0; j < 4; ++j) bj[j] = bias[cb + j * 16 + fr];
    if (which == 2) {
      u8* VT_ = (u8*)resid;
      const int zb = rb >> 11;
      const int seqb = (rb & 2047) + quad * 4;
      const int dimb = (c64 - 24) * 64;
#pragma unroll
      for (int i = 0; i < 4; ++i) {
#pragma unroll
        for (int j = 0; j < 4; ++j) {
          const int dim = dimb + j * 16 + fr;
          unsigned v01 = __builtin_amdgcn_cvt_pk_fp8_f32(acc[i][j][0] + bj[j],
                                                         acc[i][j][1] + bj[j], 0, 0);
          unsigned v23 = __builtin_amdgcn_cvt_pk_fp8_f32(acc[i][j][2] + bj[j],
                                                         acc[i][j][3] + bj[j], 0, 0);
          unsigned w = (v01 & 0xffffu) | (v23 << 16);
          *reinterpret_cast<unsigned*>(VT_ + (long)zb * D_MODEL * SEQLEN +
                                       (long)dim * SEQLEN + seqb + i * 16) = w;
        }
      }
      return;
    }
    u8* ep8 = (u8*)(smem + wv * 8192);
    u8* Cg = (u8*)Cout + (long)which * NROWS * D_MODEL;
    const int cbo = (c64 - which * 12) * 64;
#pragma unroll
    for (int i = 0; i < 4; ++i)
#pragma unroll
      for (int r = 0; r < 4; ++r) {
        const int lrow = i * 16 + quad * 4 + r;
#pragma unroll
        for (int j = 0; j < 4; ++j)
          ep8[lrow * 64 + j * 16 + fr] = f2fp8(acc[i][j][r] + bj[j]);
      }
#pragma unroll
    for (int it = 0; it < 4; ++it) {
      const int lr = it * 16 + (lane >> 2);
      const int ch = (lane & 3) << 4;
      int4 d = *(const int4*)(ep8 + lr * 64 + ch);
      *reinterpret_cast<int4*>(Cg + (long)(rb + lr) * D_MODEL + cbo + ch) = d;
    }
  } else {
    // EPI_GELU (bf16 out, tanh-form gelu)
    u16* ep16 = (u16*)(smem + wv * 8192);
    u16* Cg = (u16*)Cout + (long)z * sC;
    float bj[4];
#pragma unroll
    for (int j = 0; j < 4; ++j) bj[j] = bias[cb + j * 16 + fr];
#pragma unroll
    for (int i = 0; i < 4; ++i) {
#pragma unroll
      for (int r = 0; r < 4; ++r) {
        const int lrow = i * 16 + quad * 4 + r;
#pragma unroll
        for (int j = 0; j < 4; ++j) {
          float t = acc[i][j][r] + bj[j];
          float y = 0.7978845608f * (t + 0.044715f * t * t * t);
          float e = __expf(-2.f * fabsf(y));
          float th = (1.f - e) / (1.f + e);
          th = (y < 0.f) ? -th : th;
          ep16[lrow * 64 + j * 16 + fr] = f2bf(0.5f * t * (1.f + th));
        }
      }
    }
#pragma unroll
    for (int it = 0; it < 8; ++it) {
      const int lr = it * 8 + (lane >> 3);
      const int ch = (lane & 7) << 3;
      int4 d = *(const int4*)(ep16 + lr * 64 + ch);
      *reinterpret_cast<int4*>(Cg + (long)(rb + lr) * N + cb + ch) = d;
    }
  }
}

// ------- GEMM F8: C = A*B^T with fp8 e4m3 inputs, tile 128x256, BK=128(bytes), 8 waves -------
// K-loop halved vs bf16 (same MFMA count at 16x16x32_fp8): attacks the barrier-drain stall.
template<int EPI>
__global__ __launch_bounds__(512, 4)
void gemm_f8(const u8* __restrict__ Aall, const u8* __restrict__ Ball,
             void* __restrict__ Cout,
             int M, int N, int K,           // K in elements == bytes
             long sA, long sB, long sC,
             float* __restrict__ lsum, float scale)
{
  // 48 KB: As 128x128B [0,16K), Bs 256x128B [16K,48K); epilogue: 8 x 4 KB wave regions.
  __shared__ __align__(16) char smem[49152];
  u8* As = (u8*)smem;
  u8* Bs = (u8*)(smem + 16384);

  const int z = blockIdx.z;
  const u8* A = Aall + (long)z * sA;
  const u8* B = Ball + (long)z * sB;
  const int bm = blockIdx.x, bn = blockIdx.y;
  const int tid = (int)threadIdx.x;
  const int lane = tid & 63, wv = tid >> 6;
  const int wr = wv >> 2, wc = wv & 3;

  facc acc[4][4] = {};

  // staging: row = 128 B = 8 x 16B chunks; lds slot s of row r holds global chunk s^(r&7)
  const int srow = tid >> 3;                          // 0..63
  const int scol = (((tid & 7) ^ (srow & 7)) << 4);   // swizzled byte offset in row
  const u8* Abase = A + (long)(bm * 128) * K;
  const u8* Bbase = B + (long)(bn * 256) * K;

  const int fr = lane & 15;
  const int g0 = lane >> 4;

  for (int k0 = 0; k0 < K; k0 += 128) {
    __syncthreads();
#pragma unroll
    for (int p = 0; p < 2; ++p)    // A: 128 rows
      async16(Abase + (long)(p * 64 + srow) * K + k0 + scol, As + (p * 512 + wv * 64) * 16);
#pragma unroll
    for (int p = 0; p < 4; ++p)    // B: 256 rows
      async16(Bbase + (long)(p * 64 + srow) * K + k0 + scol, Bs + (p * 512 + wv * 64) * 16);
    __syncthreads();
#pragma unroll
    for (int s = 0; s < 4; ++s) {  // 4 K-substeps of 32 fp8
      long af[4], bfv[4];
      const int c = s * 2 + (g0 >> 1);
      const int w8 = (g0 & 1) << 3;
#pragma unroll
      for (int i = 0; i < 4; ++i) {
        const int r = wr * 64 + i * 16 + fr;
        af[i] = *(const long*)(As + r * 128 + ((c ^ (r & 7)) << 4) + w8);
      }
#pragma unroll
      for (int j = 0; j < 4; ++j) {
        const int r = wc * 64 + j * 16 + fr;
        bfv[j] = *(const long*)(Bs + r * 128 + ((c ^ (r & 7)) << 4) + w8);
      }
#pragma unroll
      for (int i = 0; i < 4; ++i)
#pragma unroll
        for (int j = 0; j < 4; ++j)
          acc[i][j] = __builtin_amdgcn_mfma_f32_16x16x32_fp8_fp8(af[i], bfv[j], acc[i][j], 0, 0, 0);
    }
  }

  __syncthreads();
  const int rb = bm * 128 + wr * 64;
  const int cb = bn * 256 + wc * 64;
  const int quad = lane >> 4;

  if constexpr (EPI == EPI_EXP) {
    // E' = exp(alpha - 3) in fp8 (range ~[e^-5, e^-1], safely inside e4m3); rowsums to lsum.
    u8* ep8 = (u8*)(smem + wv * 4096);
    u8* Cg = (u8*)Cout + (long)z * sC;
#pragma unroll
    for (int i = 0; i < 4; ++i) {
#pragma unroll
      for (int r = 0; r < 4; ++r) {
        const int lrow = i * 16 + quad * 4 + r;
        const int row = rb + lrow;
        float rs = 0.f;
#pragma unroll
        for (int j = 0; j < 4; ++j) {
          float e = __expf(acc[i][j][r] * scale - 3.0f);
          rs += e;
          ep8[lrow * 64 + j * 16 + fr] = f2fp8(e);
        }
        rs += __shfl_xor(rs, 1);
        rs += __shfl_xor(rs, 2);
        rs += __shfl_xor(rs, 4);
        rs += __shfl_xor(rs, 8);
        if (fr == 0) atomicAdd(&lsum[(long)z * M + row], rs);
      }
    }
#pragma unroll
    for (int it = 0; it < 4; ++it) {
      const int lr = it * 16 + (lane >> 2);
      const int ch = (lane & 3) << 4;
      int4 d = *(const int4*)(ep8 + lr * 64 + ch);
      *reinterpret_cast<int4*>(Cg + (long)(rb + lr) * N + cb + ch) = d;
    }
  } else {
    // EPI_DIV: bf16 out = acc / lsum, staged in two 32-row half-passes (4 KB/wave)
    u16* ep16 = (u16*)(smem + wv * 4096);
    u16* Cg = (u16*)Cout + (long)z * sC;
#pragma unroll
    for (int h = 0; h < 2; ++h) {
#pragma unroll
      for (int i2 = 0; i2 < 2; ++i2) {
        const int i = h * 2 + i2;
#pragma unroll
        for (int r = 0; r < 4; ++r) {
          const int lrow = i2 * 16 + quad * 4 + r;
          const int row = rb + h * 32 + lrow;
          const float inv = 1.f / lsum[(long)z * M + row];
#pragma unroll
          for (int j = 0; j < 4; ++j)
            ep16[lrow * 64 + j * 16 + fr] = f2bf(acc[i][j][r] * inv);
        }
      }
#pragma unroll
      for (int it = 0; it < 4; ++it) {
        const int lr = it * 8 + (lane >> 3);
        const int ch = (lane & 7) << 3;
        int4 d = *(const int4*)(ep16 + lr * 64 + ch);
        *reinterpret_cast<int4*>(Cg + (long)(rb + h * 32 + lr) * N + cb + ch) = d;
      }
    }
  }
}

// ------- GEMM B (bf16): tile 128x128, 4 waves, 256 thr — for N=768 launches -------
// launch_bounds (256,4): VGPR cap 128 >= ~92 needed. (256,5) spilled the accumulator (r7).
template<int EPI>
__global__ __launch_bounds__(256, 4)
void gemm_bt128(const u16* __restrict__ Aall, const u16* __restrict__ Ball,
                void* __restrict__ Cout,
                int M, int N, int K,
                long sA, long sB, long sC,
                const float* __restrict__ bias,
                const u16* __restrict__ resid,
                float* __restrict__ lsum,
                float scale)
{
  __shared__ __align__(16) char smem[32768];
  u16* As = (u16*)smem;
  u16* Bs = (u16*)(smem + 16384);

  const int z = blockIdx.z;
  const u16* A = Aall + (long)z * sA;
  const u16* B = Ball + (long)z * sB;
  const int bm = blockIdx.x, bn = blockIdx.y;
  const int tid = (int)threadIdx.x;
  const int lane = tid & 63, wv = tid >> 6;
  const int wr = wv >> 1, wc = wv & 1;

  facc acc[4][4] = {};

  const int srow = tid >> 3;
  const int scol = (((tid & 7) ^ (srow & 7)) << 3);
  const u16* Abase = A + (long)(bm * 128) * K;
  const u16* Bbase = B + (long)(bn * 128) * K;
  const int fr = lane & 15, g0 = lane >> 4;

  for (int k0 = 0; k0 < K; k0 += 64) {
    __syncthreads();
#pragma unroll
    for (int p = 0; p < 4; ++p) {
      async16(Abase + (long)(p * 32 + srow) * K + k0 + scol, As + (p * 256 + wv * 64) * 8);
      async16(Bbase + (long)(p * 32 + srow) * K + k0 + scol, Bs + (p * 256 + wv * 64) * 8);
    }
    __syncthreads();
#pragma unroll
    for (int h = 0; h < 2; ++h) {
      bfrag af[4], bfv[4];
      const int gh = g0 + h * 4;
#pragma unroll
      for (int i = 0; i < 4; ++i) {
        const int r = wr * 64 + i * 16 + fr;
        af[i] = *(const bfrag*)(As + r * 64 + ((gh ^ (r & 7)) << 3));
      }
#pragma unroll
      for (int j = 0; j < 4; ++j) {
        const int r = wc * 64 + j * 16 + fr;
        bfv[j] = *(const bfrag*)(Bs + r * 64 + ((gh ^ (r & 7)) << 3));
      }
#pragma unroll
      for (int i = 0; i < 4; ++i)
#pragma unroll
        for (int j = 0; j < 4; ++j)
          acc[i][j] = __builtin_amdgcn_mfma_f32_16x16x32_bf16(af[i], bfv[j], acc[i][j], 0, 0, 0);
    }
  }

  __syncthreads();
  const int rb = bm * 128 + wr * 64;
  const int cb = bn * 128 + wc * 64;
  const int quad = lane >> 4;

  // EPI_RES: bf16 out = acc + bias + bf16 residual
  float* ep32 = (float*)(smem + wv * 8192);
  u16* Cg = (u16*)Cout;
#pragma unroll
  for (int h = 0; h < 2; ++h) {
#pragma unroll
    for (int i2 = 0; i2 < 2; ++i2) {
      const int i = h * 2 + i2;
#pragma unroll
      for (int r = 0; r < 4; ++r) {
        const int lrow = i2 * 16 + quad * 4 + r;
#pragma unroll
        for (int j = 0; j < 4; ++j)
          ep32[lrow * 64 + j * 16 + fr] = acc[i][j][r];
      }
    }
#pragma unroll
    for (int it = 0; it < 8; ++it) {
      const int lr = it * 4 + (lane >> 4);
      const int ch = (lane & 15) << 2;
      float4 d = *(const float4*)(ep32 + lr * 64 + ch);
      const int row = rb + h * 32 + lr;
      const int gcol = cb + ch;
      const long gi = (long)row * N + gcol;
      ushort4 rv = *(const ushort4*)(resid + gi);
      float4 bb = *(const float4*)(bias + gcol);
      ushort4 o;
      o.x = f2bf(d.x + bb.x + bf2f(rv.x));
      o.y = f2bf(d.y + bb.y + bf2f(rv.y));
      o.z = f2bf(d.z + bb.z + bf2f(rv.z));
      o.w = f2bf(d.w + bb.w + bf2f(rv.w));
      *reinterpret_cast<ushort4*>(Cg + gi) = o;
    }
  }
  (void)lsum; (void)scale; (void)sC; (void)M;
}

// ---------------- LayerNorm over rows of 768, bf16 in ----------------
__global__ __launch_bounds__(192) void layernorm_rows(const u16* __restrict__ in,
                                                      const float* __restrict__ gamma,
                                                      const float* __restrict__ beta,
                                                      float* __restrict__ outf,
                                                      u16* __restrict__ outb) {
  const int row = blockIdx.x;
  const int t = threadIdx.x;
  ushort4 uv = ((const ushort4*)(in + (long)row * D_MODEL))[t];
  float v0 = bf2f(uv.x), v1 = bf2f(uv.y), v2 = bf2f(uv.z), v3 = bf2f(uv.w);
  float s1 = v0 + v1 + v2 + v3;
  float s2 = v0 * v0 + v1 * v1 + v2 * v2 + v3 * v3;
#pragma unroll
  for (int o = 32; o; o >>= 1) { s1 += __shfl_xor(s1, o); s2 += __shfl_xor(s2, o); }
  __shared__ float r1[3], r2[3];
  const int wv = t >> 6, ln = t & 63;
  if (ln == 0) { r1[wv] = s1; r2[wv] = s2; }
  __syncthreads();
  s1 = r1[0] + r1[1] + r1[2];
  s2 = r2[0] + r2[1] + r2[2];
  const float mu = s1 * (1.f / 768.f);
  const float var = s2 * (1.f / 768.f) - mu * mu;
  const float rstd = rsqrtf(var + 1e-12f);
  float4 gv = ((const float4*)gamma)[t];
  float4 bv = ((const float4*)beta)[t];
  float o0 = (v0 - mu) * rstd * gv.x + bv.x;
  float o1 = (v1 - mu) * rstd * gv.y + bv.y;
  float o2 = (v2 - mu) * rstd * gv.z + bv.z;
  float o3 = (v3 - mu) * rstd * gv.w + bv.w;
  if (outf) {
    float4 ov = {o0, o1, o2, o3};
    ((float4*)(outf + (long)row * D_MODEL))[t] = ov;
  }
  if (outb) {
    ushort4 ob;
    ob.x = f2bf(o0); ob.y = f2bf(o1); ob.z = f2bf(o2); ob.w = f2bf(o3);
    ((ushort4*)(outb + (long)row * D_MODEL))[t] = ob;
  }
}

// ---------------- workspace layout (bytes), stream-ordered aliasing ----------------
static const size_t OFF_WP   = 0;          // 1179648
static const size_t OFF_W1   = 1179648;    // 2359296
static const size_t OFF_W2   = 3538944;    // 2359296 -> 5898240
static const size_t OFF_LSUM = 5898240;    // 65536
static const size_t OFF_BQKV = 5963776;    // 9216 (pad to 6291456)
static const size_t OFF_QB   = 6291456;    // fp8 12582912  (QB,KB contiguous)
static const size_t OFF_KB   = 18874368;   // fp8 12582912
static const size_t OFF_VT   = 31457280;   // fp8 12582912 [dead after DIV]
static const size_t OFF_EB   = 44040192;   // fp8 33554432 [dead after DIV]
static const size_t OFF_CTX  = 77594624;   // bf16 25165824 [dead after proj]
static const size_t OFF_XB   = 102760448;  // bf16 25165824 [dead after proj]
static const size_t OFF_WQKV = 127926272;  // bf16 3538944 -> 131465216
static const size_t OFF_M1B  = 131465216;  // bf16 50331648 -> 181796864 total
// aliases: PB=QB+KB (25 MB); HB=EB head (25 MB); M2B=CTX region

extern "C" void kernel_launch(void* const* d_in, const int* in_sizes, int n_in,
                              void* d_out, int out_size, void* d_ws, size_t ws_size,
                              hipStream_t stream) {
  const float* x   = (const float*)d_in[0];
  const float* Wq  = (const float*)d_in[1];
  const float* bq  = (const float*)d_in[2];
  const float* Wk  = (const float*)d_in[3];
  const float* bk  = (const float*)d_in[4];
  const float* Wv  = (const float*)d_in[5];
  const float* bv  = (const float*)d_in[6];
  const float* Wp  = (const float*)d_in[7];
  const float* bp  = (const float*)d_in[8];
  const float* g1  = (const float*)d_in[9];
  const float* be1 = (const float*)d_in[10];
  const float* W1  = (const float*)d_in[11];
  const float* b1  = (const float*)d_in[12];
  const float* W2  = (const float*)d_in[13];
  const float* b2  = (const float*)d_in[14];
  const float* g2  = (const float*)d_in[15];
  const float* be2 = (const float*)d_in[16];

  char* ws = (char*)d_ws;
  u16*   WPB  = (u16*)(ws + OFF_WP);
  u16*   W1B  = (u16*)(ws + OFF_W1);
  u16*   W2B  = (u16*)(ws + OFF_W2);
  float* LSUM = (float*)(ws + OFF_LSUM);
  float* BQKV = (float*)(ws + OFF_BQKV);
  u8*    QB   = (u8*)(ws + OFF_QB);
  u8*    KB   = (u8*)(ws + OFF_KB);
  u8*    VT   = (u8*)(ws + OFF_VT);
  u8*    EB   = (u8*)(ws + OFF_EB);
  u16*   CTX  = (u16*)(ws + OFF_CTX);
  u16*   XB   = (u16*)(ws + OFF_XB);
  u16*   WQKV = (u16*)(ws + OFF_WQKV);
  u16*   M1B  = (u16*)(ws + OFF_M1B);
  // aliases (stream-ordered lifetimes)
  u16*   PB   = (u16*)(ws + OFF_QB);    // after EXP frees QB+KB
  u16*   HB   = (u16*)(ws + OFF_EB);    // after DIV frees EB
  u16*   M2B  = (u16*)(ws + OFF_CTX);   // after proj frees CTX

  dim3 blk(256), blkg(512), blkl(192);

  // all f32->bf16 conversions + bias concat + LSUM zero, one kernel
  cvt_all<<<dim3(16915), blk, 0, stream>>>(x, Wq, Wk, Wv, Wp, W1, W2, bq, bk, bv,
                                           XB, WQKV, WPB, W1B, W2B, BQKV, LSUM);

  // fused QKV projection (bf16 core, fp8 outputs): Q,K row-major fp8; V -> VT fp8 transposed
  gemm_bt<EPI_QKV><<<dim3(128, 9, 1), blkg, 0, stream>>>(XB, WQKV, QB,
      NROWS, 3 * D_MODEL, D_MODEL, 0, 0, 0, BQKV, (const u16*)VT, nullptr, 0.f);

  // scores: E' = exp(Q K^T / sqrt(D) - 3) fp8, row sums into LSUM (offset cancels in DIV)
  const float sc = 1.0f / sqrtf((float)D_MODEL);
  gemm_f8<EPI_EXP><<<dim3(16, 8, 8), blkg, 0, stream>>>(QB, KB, EB,
      SEQLEN, SEQLEN, D_MODEL,
      (long)SEQLEN * D_MODEL, (long)SEQLEN * D_MODEL, (long)SEQLEN * SEQLEN,
      LSUM, sc);
  // context: Ctx = (E' V) / lsum'  (bf16 out)
  gemm_f8<EPI_DIV><<<dim3(16, 3, 8), blkg, 0, stream>>>(EB, VT, CTX,
      SEQLEN, D_MODEL, SEQLEN,
      (long)SEQLEN * SEQLEN, (long)D_MODEL * SEQLEN, (long)SEQLEN * D_MODEL,
      LSUM, 0.f);
  // proj + residual (bf16): PB = bf16(x + Ctx Wp^T + bp)
  gemm_bt128<EPI_RES><<<dim3(128, 6, 1), blk, 0, stream>>>(CTX, WPB, PB,
      NROWS, D_MODEL, D_MODEL, 0, 0, 0, bp, XB, nullptr, 0.f);
  // LN1 -> HB (bf16)
  layernorm_rows<<<dim3(NROWS), blkl, 0, stream>>>(PB, g1, be1, nullptr, HB);
  // MLP1 + tanh-gelu -> M1B (bf16)
  gemm_bt<EPI_GELU><<<dim3(128, 6, 1), blkg, 0, stream>>>(HB, W1B, M1B,
      NROWS, D_HID, D_MODEL, 0, 0, 0, b1, nullptr, nullptr, 0.f);
  // MLP2 + residual (bf16): M2B = bf16(h + M1 W2^T + b2)
  gemm_bt128<EPI_RES><<<dim3(128, 6, 1), blk, 0, stream>>>(M1B, W2B, M2B,
      NROWS, D_MODEL, D_HID, 0, 0, 0, b2, HB, nullptr, 0.f);
  // LN2 -> d_out (fp32)
  layernorm_rows<<<dim3(NROWS), blkl, 0, stream>>>(M2B, g2, be2, (float*)d_out, nullptr);

  (void)in_sizes; (void)n_in; (void)out_size; (void)ws_size;
}